// Round 5
// baseline (560.184 us; speedup 1.0000x reference)
//
#include <hip/hip_runtime.h>

// Problem constants: B=65536, A=8, E=128, K=2E=256
typedef __attribute__((ext_vector_type(8))) short short8;   // 8 bf16 = 4 VGPRs
typedef __attribute__((ext_vector_type(4))) short bfx4;     // 4 bf16 = 2 VGPRs
typedef __attribute__((ext_vector_type(4))) float floatx4;  // MFMA accumulator

__device__ inline short f2bf(float f) {
  // round-to-nearest-even fp32 -> bf16 (inputs finite)
  unsigned u = __builtin_bit_cast(unsigned, f);
  unsigned r = u + 0x7fffu + ((u >> 16) & 1u);
  return (short)(r >> 16);
}

__device__ inline bfx4 cvt4(float4 a) {
  bfx4 r;
  r[0] = f2bf(a.x); r[1] = f2bf(a.y); r[2] = f2bf(a.z); r[3] = f2bf(a.w);
  return r;
}

// ---------------------------------------------------------------------------
// Phase 1: fold W_agg into proj, emitting Mt in FRAGMENT-MAJOR layout:
//   value(a,j,k) = sum_i W_agg[i][k] * proj[a][i][j]   (bf16)
//   stored at Mt[((a*8 + ks)*8 + nt)*512 + l16*32 + quad*8 + e]
//     where ks=k>>5, quad=(k>>3)&3, e=k&7, nt=j>>4, l16=j&15
//   -> in gemm, one wave's 8 B-fragments for a K-step are one contiguous
//      4 KB region (perfectly coalesced L2 reads).
//   bias2[a][j] = sum_i b_agg[i] * proj[a][i][j]       (fp32)
// ---------------------------------------------------------------------------
__global__ __launch_bounds__(256) void prep_M(
    const float* __restrict__ W, const float* __restrict__ proj,
    const float* __restrict__ bvec, short* __restrict__ Mt,
    float* __restrict__ bias2) {
  int blk = blockIdx.x;
  int a = blk >> 7, j = blk & 127;
  int k = threadIdx.x;  // 0..255
  const float* pj = proj + a * 16384 + j;  // proj[a][i][j], stride 128
  float acc = 0.f;
#pragma unroll 4
  for (int i = 0; i < 128; ++i)
    acc += W[i * 256 + k] * pj[i * 128];
  int ks = k >> 5, quad = (k >> 3) & 3, e = k & 7;
  int nt = j >> 4, l16 = j & 15;
  Mt[((a * 8 + ks) * 8 + nt) * 512 + l16 * 32 + quad * 8 + e] = f2bf(acc);
  if (k == 0) {
    float b = 0.f;
    for (int i = 0; i < 128; ++i) b += bvec[i] * pj[i * 128];
    bias2[a * 128 + j] = b;
  }
}

// ---------------------------------------------------------------------------
// Phase 2: out[b,a,j] = [img[b,:] | edge[b,a,:]] @ M[a] + bias2[a,:]
//
// v5 — row-contiguous decomposition. One block = 16 batch rows x ALL 8
// attribute types; 512 threads = 8 waves; wave w owns a=w.
//  * edge read / out write are CONTIGUOUS 4 KB-per-row streams (vs 512 B
//    slices strided 4 KB in v0-v4) -> HBM page locality.
//  * A staged in ONE burst (9 outstanding float4/thread, 72 KB/block in
//    flight), ONE barrier total, then waves run fully independently:
//    no per-K-step barrier coupling (v0/v4's exposed-latency defect).
//  * B (Mt[w], 64 KB, L2-resident; 512 KB total fits every XCD's 4 MB L2)
//    read global->reg in fragment-major contiguous 4 KB wave accesses.
//  * LDS rows padded +8 shorts -> 2-way bank alias only (free).
// ---------------------------------------------------------------------------
__global__ __launch_bounds__(512, 4) void gemm_main(
    const float* __restrict__ img, const float* __restrict__ edge,
    const short* __restrict__ Mt, const float* __restrict__ bias2,
    float* __restrict__ out) {
  __shared__ short imgS[16 * 136];    // [row][128+8]  4.25 KB
  __shared__ short edgeS[16 * 1032];  // [row][1024+8] 32.25 KB

  const int tid = threadIdx.x;            // 0..511
  const int b0 = blockIdx.x << 4;         // 16 rows per block
  const int wave = tid >> 6;              // 0..7 == attribute type a
  const int lane = tid & 63;
  const int quad = lane >> 4, l16 = lane & 15;

  // ---- stage burst: img 512 float4 (1/thread), edge 4096 float4 (8/thread)
  float4 vi = *(const float4*)(img + (size_t)(b0 + (tid >> 5)) * 128 + (tid & 31) * 4);
  float4 ve[8];
#pragma unroll
  for (int i = 0; i < 8; ++i) {
    int f = i * 512 + tid;  // float4 index; row = f>>8, col4 = f&255
    ve[i] = *(const float4*)(edge + (size_t)(b0 + (f >> 8)) * 1024 + (f & 255) * 4);
  }
  *(bfx4*)((char*)imgS + (tid >> 5) * 272 + (tid & 31) * 8) = cvt4(vi);
#pragma unroll
  for (int i = 0; i < 8; ++i) {
    int f = i * 512 + tid;
    *(bfx4*)((char*)edgeS + (f >> 8) * 2064 + (f & 255) * 8) = cvt4(ve[i]);
  }
  __syncthreads();  // the ONLY barrier

  // ---- per-wave GEMM: 16 rows x 128 cols, K=256 in 8 steps, 8 n-tiles
  const short* mB = Mt + wave * 32768 + l16 * 32 + quad * 8;
  floatx4 acc[8] = {};
#pragma unroll
  for (int ks = 0; ks < 8; ++ks) {
    short8 af;  // A[m=l16][k = ks*32 + quad*8 ..+7]
    if (ks < 4)
      af = *(const short8*)((const char*)imgS + l16 * 272 + (ks * 32 + quad * 8) * 2);
    else
      af = *(const short8*)((const char*)edgeS +
                            l16 * 2064 + (wave * 128 + (ks - 4) * 32 + quad * 8) * 2);
#pragma unroll
    for (int nt = 0; nt < 8; ++nt) {
      short8 bf = *(const short8*)(mB + ks * 4096 + nt * 512);
      acc[nt] = __builtin_amdgcn_mfma_f32_16x16x32_bf16(af, bf, acc[nt], 0, 0, 0);
    }
  }

  // ---- epilogue: C/D layout col=l16 (j), row=quad*4+r (batch row)
  float bias[8];
#pragma unroll
  for (int nt = 0; nt < 8; ++nt) bias[nt] = bias2[wave * 128 + nt * 16 + l16];
  float* ob = out + (size_t)b0 * 1024 + wave * 128 + l16;
#pragma unroll
  for (int nt = 0; nt < 8; ++nt)
#pragma unroll
    for (int r = 0; r < 4; ++r)
      ob[(size_t)(quad * 4 + r) * 1024 + nt * 16] = acc[nt][r] + bias[nt];
}

extern "C" void kernel_launch(void* const* d_in, const int* in_sizes, int n_in,
                              void* d_out, int out_size, void* d_ws,
                              size_t ws_size, hipStream_t stream) {
  const float* img  = (const float*)d_in[0];  // [65536,128]
  const float* edge = (const float*)d_in[1];  // [65536,8,128]
  const float* W    = (const float*)d_in[2];  // [128,256]
  const float* bv   = (const float*)d_in[3];  // [128]
  const float* proj = (const float*)d_in[4];  // [8,128,128]
  float* out = (float*)d_out;                 // [65536,8,128]

  short* Mt = (short*)d_ws;                         // 8*128*256 bf16 = 512 KB
  float* bias2 = (float*)((char*)d_ws + 8 * 128 * 256 * 2);  // 4 KB

  prep_M<<<1024, 256, 0, stream>>>(W, proj, bv, Mt, bias2);
  gemm_main<<<4096, 512, 0, stream>>>(img, edge, Mt, bias2, out);
}

// Round 7
// 559.803 us; speedup vs baseline: 1.0007x; 1.0007x over previous
//
#include <hip/hip_runtime.h>

// Problem constants: B=65536, A=8, E=128, K=2E=256
typedef __attribute__((ext_vector_type(8))) short short8;   // 8 bf16 = 4 VGPRs
typedef __attribute__((ext_vector_type(4))) short bfx4;     // 4 bf16 = 2 VGPRs
typedef __attribute__((ext_vector_type(4))) float floatx4;  // MFMA accumulator

__device__ inline short f2bf(float f) {
  // round-to-nearest-even fp32 -> bf16 (inputs finite)
  unsigned u = __builtin_bit_cast(unsigned, f);
  unsigned r = u + 0x7fffu + ((u >> 16) & 1u);
  return (short)(r >> 16);
}

__device__ inline bfx4 cvt4(float4 a) {
  bfx4 r;
  r[0] = f2bf(a.x); r[1] = f2bf(a.y); r[2] = f2bf(a.z); r[3] = f2bf(a.w);
  return r;
}

// Keep-alive pins: force the register allocator to keep a GROUP of 16-B loads
// live simultaneously -> all issued before one latency drain (R5 showed the
// compiler otherwise serializes them at VGPR_Count=32). 128-bit operands are
// not legal for "v", so pin 32-bit components via uint4 bit_casts.
__device__ __forceinline__ void pin1(const float4& a) {
  uint4 A = __builtin_bit_cast(uint4, a);
  asm volatile("" ::"v"(A.x), "v"(A.y), "v"(A.z), "v"(A.w));
}
__device__ __forceinline__ void pin4f(const float4& a, const float4& b,
                                      const float4& c, const float4& d) {
  uint4 A = __builtin_bit_cast(uint4, a), B = __builtin_bit_cast(uint4, b);
  uint4 C = __builtin_bit_cast(uint4, c), D = __builtin_bit_cast(uint4, d);
  asm volatile("" ::"v"(A.x), "v"(A.y), "v"(A.z), "v"(A.w), "v"(B.x), "v"(B.y),
               "v"(B.z), "v"(B.w), "v"(C.x), "v"(C.y), "v"(C.z), "v"(C.w),
               "v"(D.x), "v"(D.y), "v"(D.z), "v"(D.w));
}
__device__ __forceinline__ void pin4s(const short8& a, const short8& b,
                                      const short8& c, const short8& d) {
  uint4 A = __builtin_bit_cast(uint4, a), B = __builtin_bit_cast(uint4, b);
  uint4 C = __builtin_bit_cast(uint4, c), D = __builtin_bit_cast(uint4, d);
  asm volatile("" ::"v"(A.x), "v"(A.y), "v"(A.z), "v"(A.w), "v"(B.x), "v"(B.y),
               "v"(B.z), "v"(B.w), "v"(C.x), "v"(C.y), "v"(C.z), "v"(C.w),
               "v"(D.x), "v"(D.y), "v"(D.z), "v"(D.w));
}

// ---------------------------------------------------------------------------
// Phase 1: fold W_agg into proj, emitting Mt in FRAGMENT-MAJOR layout:
//   value(a,j,k) = sum_i W_agg[i][k] * proj[a][i][j]   (bf16)
//   stored at Mt[((a*8 + ks)*8 + nt)*512 + l16*32 + quad*8 + e]
//   -> one wave's B-fragment for (ks,nt) is one contiguous 1 KB L2 read.
//   bias2[a][j] = sum_i b_agg[i] * proj[a][i][j]       (fp32)
// ---------------------------------------------------------------------------
__global__ __launch_bounds__(256) void prep_M(
    const float* __restrict__ W, const float* __restrict__ proj,
    const float* __restrict__ bvec, short* __restrict__ Mt,
    float* __restrict__ bias2) {
  int blk = blockIdx.x;
  int a = blk >> 7, j = blk & 127;
  int k = threadIdx.x;  // 0..255
  const float* pj = proj + a * 16384 + j;  // proj[a][i][j], stride 128
  float acc = 0.f;
#pragma unroll 4
  for (int i = 0; i < 128; ++i)
    acc += W[i * 256 + k] * pj[i * 128];
  int ks = k >> 5, quad = (k >> 3) & 3, e = k & 7;
  int nt = j >> 4, l16 = j & 15;
  Mt[((a * 8 + ks) * 8 + nt) * 512 + l16 * 32 + quad * 8 + e] = f2bf(acc);
  if (k == 0) {
    float b = 0.f;
    for (int i = 0; i < 128; ++i) b += bvec[i] * pj[i * 128];
    bias2[a * 128 + j] = b;
  }
}

// ---------------------------------------------------------------------------
// Phase 2: out[b,a,j] = [img[b,:] | edge[b,a,:]] @ M[a] + bias2[a,:]
//
// v6b = v5 structure (16 rows x all 8 attrs per block, 8 waves, wave w owns
// a=w, ONE barrier, contiguous edge/out streams) + pinned load groups to
// force memory-level parallelism the compiler refused at VGPR_Count=32.
// ---------------------------------------------------------------------------
__global__ __launch_bounds__(512, 4) void gemm_main(
    const float* __restrict__ img, const float* __restrict__ edge,
    const short* __restrict__ Mt, const float* __restrict__ bias2,
    float* __restrict__ out) {
  __shared__ short imgS[16 * 136];    // [row][128+8]  4.25 KB
  __shared__ short edgeS[16 * 1032];  // [row][1024+8] 32.25 KB

  const int tid = threadIdx.x;            // 0..511
  const int b0 = blockIdx.x << 4;         // 16 rows per block
  const int wave = tid >> 6;              // 0..7 == attribute type a
  const int lane = tid & 63;
  const int quad = lane >> 4, l16 = lane & 15;

  // ---- stage burst: img 512 float4 (1/thread), edge 4096 float4 (8/thread)
  const float* ib = img + (size_t)(b0 + (tid >> 5)) * 128 + (tid & 31) * 4;
  const float* eb = edge + (size_t)b0 * 1024;
#define EADDR(i) (eb + (size_t)(((i) * 512 + tid) >> 8) * 1024 + (((i) * 512 + tid) & 255) * 4)
  float4 vi = *(const float4*)ib;
  float4 e0 = *(const float4*)EADDR(0);
  float4 e1 = *(const float4*)EADDR(1);
  float4 e2 = *(const float4*)EADDR(2);
  float4 e3 = *(const float4*)EADDR(3);
  pin1(vi);
  pin4f(e0, e1, e2, e3);  // 5 loads in flight, one drain
  float4 e4 = *(const float4*)EADDR(4);
  float4 e5 = *(const float4*)EADDR(5);
  float4 e6 = *(const float4*)EADDR(6);
  float4 e7 = *(const float4*)EADDR(7);
  pin4f(e4, e5, e6, e7);  // 4 more in flight
#undef EADDR

  *(bfx4*)((char*)imgS + (tid >> 5) * 272 + (tid & 31) * 8) = cvt4(vi);
#define ESTORE(i, v)                                                        \
  *(bfx4*)((char*)edgeS + (((i) * 512 + tid) >> 8) * 2064 +                 \
           (((i) * 512 + tid) & 255) * 8) = cvt4(v)
  ESTORE(0, e0); ESTORE(1, e1); ESTORE(2, e2); ESTORE(3, e3);
  ESTORE(4, e4); ESTORE(5, e5); ESTORE(6, e6); ESTORE(7, e7);
#undef ESTORE
  __syncthreads();  // the ONLY barrier

  // ---- per-wave GEMM: 16 rows x 128 cols, K=256 in 8 steps, 8 n-tiles
  const short* mB = Mt + wave * 32768 + l16 * 32 + quad * 8;
  floatx4 acc[8] = {};
#pragma unroll
  for (int ks = 0; ks < 8; ++ks) {
    short8 af;  // A[m=l16][k = ks*32 + quad*8 ..+7]
    if (ks < 4)
      af = *(const short8*)((const char*)imgS + l16 * 272 + (ks * 32 + quad * 8) * 2);
    else
      af = *(const short8*)((const char*)edgeS +
                            l16 * 2064 + (wave * 128 + (ks - 4) * 32 + quad * 8) * 2);
    // load B fragments in pinned groups of 4 -> 4-deep L2 pipeline each
    short8 bf0 = *(const short8*)(mB + ks * 4096 + 0 * 512);
    short8 bf1 = *(const short8*)(mB + ks * 4096 + 1 * 512);
    short8 bf2 = *(const short8*)(mB + ks * 4096 + 2 * 512);
    short8 bf3 = *(const short8*)(mB + ks * 4096 + 3 * 512);
    pin4s(bf0, bf1, bf2, bf3);
    short8 bf4 = *(const short8*)(mB + ks * 4096 + 4 * 512);
    short8 bf5 = *(const short8*)(mB + ks * 4096 + 5 * 512);
    short8 bf6 = *(const short8*)(mB + ks * 4096 + 6 * 512);
    short8 bf7 = *(const short8*)(mB + ks * 4096 + 7 * 512);
    pin4s(bf4, bf5, bf6, bf7);
    acc[0] = __builtin_amdgcn_mfma_f32_16x16x32_bf16(af, bf0, acc[0], 0, 0, 0);
    acc[1] = __builtin_amdgcn_mfma_f32_16x16x32_bf16(af, bf1, acc[1], 0, 0, 0);
    acc[2] = __builtin_amdgcn_mfma_f32_16x16x32_bf16(af, bf2, acc[2], 0, 0, 0);
    acc[3] = __builtin_amdgcn_mfma_f32_16x16x32_bf16(af, bf3, acc[3], 0, 0, 0);
    acc[4] = __builtin_amdgcn_mfma_f32_16x16x32_bf16(af, bf4, acc[4], 0, 0, 0);
    acc[5] = __builtin_amdgcn_mfma_f32_16x16x32_bf16(af, bf5, acc[5], 0, 0, 0);
    acc[6] = __builtin_amdgcn_mfma_f32_16x16x32_bf16(af, bf6, acc[6], 0, 0, 0);
    acc[7] = __builtin_amdgcn_mfma_f32_16x16x32_bf16(af, bf7, acc[7], 0, 0, 0);
  }

  // ---- epilogue: C/D layout col=l16 (j), row=quad*4+r (batch row)
  float bias[8];
#pragma unroll
  for (int nt = 0; nt < 8; ++nt) bias[nt] = bias2[wave * 128 + nt * 16 + l16];
  float* ob = out + (size_t)b0 * 1024 + wave * 128 + l16;
#pragma unroll
  for (int nt = 0; nt < 8; ++nt)
#pragma unroll
    for (int r = 0; r < 4; ++r)
      ob[(size_t)(quad * 4 + r) * 1024 + nt * 16] = acc[nt][r] + bias[nt];
}

extern "C" void kernel_launch(void* const* d_in, const int* in_sizes, int n_in,
                              void* d_out, int out_size, void* d_ws,
                              size_t ws_size, hipStream_t stream) {
  const float* img  = (const float*)d_in[0];  // [65536,128]
  const float* edge = (const float*)d_in[1];  // [65536,8,128]
  const float* W    = (const float*)d_in[2];  // [128,256]
  const float* bv   = (const float*)d_in[3];  // [128]
  const float* proj = (const float*)d_in[4];  // [8,128,128]
  float* out = (float*)d_out;                 // [65536,8,128]

  short* Mt = (short*)d_ws;                         // 8*128*256 bf16 = 512 KB
  float* bias2 = (float*)((char*)d_ws + 8 * 128 * 256 * 2);  // 4 KB

  prep_M<<<1024, 256, 0, stream>>>(W, proj, bv, Mt, bias2);
  gemm_main<<<4096, 512, 0, stream>>>(img, edge, Mt, bias2, out);
}